// Round 2
// baseline (277.532 us; speedup 1.0000x reference)
//
#include <hip/hip_runtime.h>
#include <math.h>
#include <stdint.h>

// Problem constants
#define BB    8
#define DIN   1024
#define TT    2048
#define KK    8192
#define DCB   8
#define NPOS  (BB*TT)         // 16384
#define KCHUNKS 64
#define KCH     (KK/KCHUNKS)  // 128
#define MARGIN  3e-4f         // provably covers fp32 eval err (~1e-5) + 7-bit packing err (~1.2e-4)

// d_out layout (float32):
#define OFF_ZQOUT  0
#define OFF_COMMIT 16777216
#define OFF_CBLOSS 16777224
#define OFF_IDX    16777232
#define OFF_ZE     16793616

// ---------------- kernel 1: prep (44 blocks, parallel roles) ----------------
// blocks 0..7   : w_in row norm (fp64)
// blocks 8..11  : w_out rows (fp32)
// blocks 12..43 : codebook normalize (fp64 + fp32 mirrors)
__global__ __launch_bounds__(256) void k_prep(
    const float* __restrict__ in_v, const float* __restrict__ in_g,
    const float* __restrict__ out_v, const float* __restrict__ out_g,
    const float* __restrict__ cb,
    double* __restrict__ w_in_d, float* __restrict__ w_out_f,
    double* __restrict__ cb_n, double* __restrict__ s_k,
    float* __restrict__ cbn_f, float* __restrict__ skp_f,
    double* __restrict__ lossS, int* __restrict__ counter)
{
    __shared__ double red[256];
    int tid = threadIdx.x;
    int blk = blockIdx.x;
    if (blk == 0) {
        if (tid < 16) lossS[tid] = 0.0;
        if (tid == 16) *counter = 0;
    }
    if (blk < 8) {
        int r = blk;
        double s = 0.0;
        for (int i = tid; i < DIN; i += 256) {
            double v = (double)in_v[r*DIN + i];
            s += v*v;
        }
        red[tid] = s; __syncthreads();
        for (int off = 128; off > 0; off >>= 1) {
            if (tid < off) red[tid] += red[tid+off];
            __syncthreads();
        }
        double scale = (double)in_g[r] / sqrt(red[0]);
        for (int i = tid; i < DIN; i += 256)
            w_in_d[r*DIN + i] = scale * (double)in_v[r*DIN + i];
    } else if (blk < 12) {
        int o = (blk-8)*256 + tid;
        float vv[DCB];
        double s = 0.0;
        #pragma unroll
        for (int d = 0; d < DCB; ++d) {
            vv[d] = out_v[o*DCB + d];
            s += (double)vv[d]*(double)vv[d];
        }
        double scale = (double)out_g[o] / sqrt(s);
        #pragma unroll
        for (int d = 0; d < DCB; ++d)
            w_out_f[o*DCB + d] = (float)(scale * (double)vv[d]);
    } else {
        int k = (blk-12)*256 + tid;
        double v[DCB]; double s = 0.0;
        #pragma unroll
        for (int d = 0; d < DCB; ++d) {
            v[d] = (double)cb[k*DCB + d];
            s += v[d]*v[d];
        }
        double nrm = sqrt(s);
        if (nrm < 1e-12) nrm = 1e-12;
        double s2 = 0.0;
        #pragma unroll
        for (int d = 0; d < DCB; ++d) {
            double t = v[d] / nrm;
            cb_n[(size_t)k*DCB + d] = t;
            cbn_f[(size_t)k*DCB + d] = (float)t;
            s2 += t*t;
        }
        s_k[k] = s2;
        skp_f[k] = (float)(s2 + 4.0);   // shift => dist' = skp - 2*dot in [3,7], always positive
    }
}

// ---------------- kernel 2: fused in-projection + reduce (fp64) -------------
// grid NPOS/32 = 512 blocks, block 256 = 32 pos x 8 i-chunks of 128.
// Summation order identical to R1 (chunks of 128 ascending, then bias) =>
// bit-identical z_e / enc_n / q_s to the kernel that passed.
__global__ __launch_bounds__(256) void k_inproj(
    const float* __restrict__ z, const double* __restrict__ w_in_d,
    const float* __restrict__ in_b,
    float* __restrict__ ze_out, double* __restrict__ enc_n,
    double* __restrict__ q_s, float* __restrict__ enc2_f)
{
    __shared__ double wl[DIN*DCB];   // 64 KB, w_in in [o][i] layout
    __shared__ double red[2048];     // 16 KB, reused twice

    int tid = threadIdx.x;
    for (int x = tid; x < DIN*DCB; x += 256) wl[x] = w_in_d[x];
    __syncthreads();

    int p = tid & 31;        // pos within block
    int q = tid >> 5;        // i-chunk 0..7
    int pos = blockIdx.x*32 + p;
    int b = pos >> 11, t = pos & (TT-1);

    const float* zp = z + ((size_t)b*DIN + (size_t)q*128)*TT + t;
    double acc[DCB] = {0,0,0,0,0,0,0,0};
    for (int ii = 0; ii < 128; ++ii) {
        double zv = (double)zp[(size_t)ii*TT];
        int wbase = q*128 + ii;
        #pragma unroll
        for (int o = 0; o < DCB; ++o) acc[o] += wl[o*DIN + wbase] * zv;
    }
    #pragma unroll
    for (int o = 0; o < DCB; ++o) red[(q*32 + p)*DCB + o] = acc[o];
    __syncthreads();

    // 256 threads = 32 pos x 8 o : sum 8 chunks sequentially (ascending), add bias
    int p2 = tid >> 3, o2 = tid & 7;
    double s = 0.0;
    for (int q2 = 0; q2 < 8; ++q2) s += red[(q2*32 + p2)*DCB + o2];
    s += (double)in_b[o2];
    __syncthreads();
    red[p2*DCB + o2] = s;    // reuse as [32][8] final values
    __syncthreads();

    if (tid < 32) {
        int pos3 = blockIdx.x*32 + tid;
        int b3 = pos3 >> 11, t3 = pos3 & (TT-1);
        double v[DCB]; double n2 = 0.0;
        #pragma unroll
        for (int o = 0; o < DCB; ++o) {
            v[o] = red[tid*DCB + o];
            n2 += v[o]*v[o];
            ze_out[((size_t)b3*DCB + o)*TT + t3] = (float)v[o];
        }
        double nrm = sqrt(n2);
        if (nrm < 1e-12) nrm = 1e-12;
        double s2 = 0.0;
        #pragma unroll
        for (int o = 0; o < DCB; ++o) {
            double e = v[o] / nrm;
            enc_n[(size_t)pos3*DCB + o] = e;
            enc2_f[(size_t)pos3*DCB + o] = (float)(-2.0 * e);
            s2 += e*e;
        }
        q_s[pos3] = s2;
    }
}

// ---------------- kernel 3: fp32 packed-key argmin screen --------------------
// grid (16 qtiles, 64 kchunks) = 1024 blocks. dist' = skp - 2*dot > 0 always;
// positive-float bit pattern is int-ordered, so pack 7-bit local k into low
// mantissa bits and track best/second-best with pure int min/max.
__global__ __launch_bounds__(256) void k_argmin32(
    const float* __restrict__ enc2_f, const float* __restrict__ cbn_f,
    const float* __restrict__ skp_f,
    int* __restrict__ d1key, int* __restrict__ d2key)
{
    __shared__ float cbl[KCH*DCB];   // 4 KB
    __shared__ float skl[KCH];       // 512 B
    int tid = threadIdx.x;
    int qt = blockIdx.x, kc = blockIdx.y, kbase = kc*KCH;

    for (int x = tid; x < KCH*DCB; x += 256) cbl[x] = cbn_f[(size_t)kbase*DCB + x];
    for (int x = tid; x < KCH; x += 256) skl[x] = skp_f[kbase + x];
    __syncthreads();

    float e[4][DCB]; int d1[4], d2[4];
    #pragma unroll
    for (int j = 0; j < 4; ++j) {
        int qq = qt*1024 + j*256 + tid;
        #pragma unroll
        for (int d = 0; d < DCB; ++d) e[j][d] = enc2_f[(size_t)qq*DCB + d];
        d1[j] = 0x7F800000; d2[j] = 0x7F800000;
    }

    const float4* cb4 = (const float4*)cbl;
    for (int kk = 0; kk < KCH; ++kk) {
        float4 ca = cb4[kk*2], cbv = cb4[kk*2+1];
        float sk = skl[kk];
        #pragma unroll
        for (int j = 0; j < 4; ++j) {
            float acc = sk;
            acc = fmaf(ca.x,  e[j][0], acc);
            acc = fmaf(ca.y,  e[j][1], acc);
            acc = fmaf(ca.z,  e[j][2], acc);
            acc = fmaf(ca.w,  e[j][3], acc);
            acc = fmaf(cbv.x, e[j][4], acc);
            acc = fmaf(cbv.y, e[j][5], acc);
            acc = fmaf(cbv.z, e[j][6], acc);
            acc = fmaf(cbv.w, e[j][7], acc);
            int key = (int)((__float_as_uint(acc) & 0xFFFFFF80u) | (unsigned)kk);
            int m = max(key, d1[j]);      // old d1
            d2[j] = min(d2[j], m);
            d1[j] = min(d1[j], key);
        }
    }
    #pragma unroll
    for (int j = 0; j < 4; ++j) {
        int qq = qt*1024 + j*256 + tid;
        d1key[(size_t)kc*NPOS + qq] = d1[j];
        d2key[(size_t)kc*NPOS + qq] = d2[j];
    }
}

// ---------------- kernel 4: merge chunks, flag near-ties, loss (unflagged) --
__global__ __launch_bounds__(256) void k_merge(
    const int* __restrict__ d1key, const int* __restrict__ d2key,
    const float* __restrict__ cb, const float* __restrict__ ze,
    float* __restrict__ idx_f, int* __restrict__ idx_i,
    int* __restrict__ flaglist, int* __restrict__ counter,
    double* __restrict__ lossS)
{
    __shared__ double red[256];
    int tid = threadIdx.x;
    int pos = blockIdx.x*256 + tid;
    int b = pos >> 11, t = pos & (TT-1);

    int bits1 = 0x7F800000, bits2 = 0x7F800000, gi = 0;
    for (int c = 0; c < KCHUNKS; ++c) {    // ascending => first-min on ties
        int k1 = d1key[(size_t)c*NPOS + pos];
        int k2 = d2key[(size_t)c*NPOS + pos];
        int db = k1 & 0xFFFFFF80;
        int b2 = k2 & 0xFFFFFF80;
        if (db < bits1) {
            bits2 = min(bits2, min(bits1, b2));
            bits1 = db;
            gi = c*KCH + (k1 & 0x7F);
        } else {
            bits2 = min(bits2, db);
        }
    }
    float d1f = __int_as_float(bits1);
    float d2f = __int_as_float(bits2);
    bool flag = (d2f - d1f) < MARGIN;

    idx_f[pos] = (float)gi;     // provisional; refine overwrites flagged
    idx_i[pos] = gi;
    if (flag) {
        int s = atomicAdd(counter, 1);
        flaglist[s] = pos;
    }

    double ssum = 0.0;
    if (!flag) {
        #pragma unroll
        for (int d = 0; d < DCB; ++d) {
            double zev = (double)ze[((size_t)b*DCB + d)*TT + t];
            double zqv = (double)cb[gi*DCB + d];
            double diff = zev - zqv;
            ssum += diff*diff;
        }
    }
    red[tid] = ssum; __syncthreads();
    for (int off = 128; off > 0; off >>= 1) {
        if (tid < off) red[tid] += red[tid+off];
        __syncthreads();
    }
    if (tid == 0) atomicAdd(&lossS[b], red[0]);
}

// ---------------- kernel 5: fp64 refine for flagged queries -----------------
// One wave per flagged query; lanes split k; lexicographic first-min.
__global__ __launch_bounds__(256) void k_refine(
    const double* __restrict__ enc_n, const double* __restrict__ q_s,
    const double* __restrict__ cb_n, const double* __restrict__ s_k,
    const float* __restrict__ cb, const float* __restrict__ ze,
    const int* __restrict__ flaglist, const int* __restrict__ counter,
    float* __restrict__ idx_f, int* __restrict__ idx_i,
    double* __restrict__ lossS)
{
    int tid = threadIdx.x;
    int wave = blockIdx.x*4 + (tid >> 6);
    int lane = tid & 63;
    int n = *counter;
    int nwaves = gridDim.x*4;

    for (int f = wave; f < n; f += nwaves) {
        int pos = flaglist[f];
        double e0 = enc_n[(size_t)pos*DCB + 0], e1 = enc_n[(size_t)pos*DCB + 1];
        double e2 = enc_n[(size_t)pos*DCB + 2], e3 = enc_n[(size_t)pos*DCB + 3];
        double e4 = enc_n[(size_t)pos*DCB + 4], e5 = enc_n[(size_t)pos*DCB + 5];
        double e6 = enc_n[(size_t)pos*DCB + 6], e7 = enc_n[(size_t)pos*DCB + 7];
        double qs = q_s[pos];
        double bd = 1e300; int bi = 1 << 30;
        for (int k = lane; k < KK; k += 64) {       // ascending per lane
            const double* c = cb_n + (size_t)k*DCB;
            double dot = e0*c[0] + e1*c[1] + e2*c[2] + e3*c[3]
                       + e4*c[4] + e5*c[5] + e6*c[6] + e7*c[7];
            double dist = qs - 2.0*dot + s_k[k];    // same expression as R1 (passed)
            if (dist < bd) { bd = dist; bi = k; }
        }
        for (int off = 32; off > 0; off >>= 1) {
            double od = __shfl_down(bd, off, 64);
            int    oi = __shfl_down(bi, off, 64);
            if (od < bd || (od == bd && oi < bi)) { bd = od; bi = oi; }
        }
        if (lane == 0) {
            int b = pos >> 11, t = pos & (TT-1);
            idx_f[pos] = (float)bi;
            idx_i[pos] = bi;
            double ssum = 0.0;
            #pragma unroll
            for (int d = 0; d < DCB; ++d) {
                double zev = (double)ze[((size_t)b*DCB + d)*TT + t];
                double zqv = (double)cb[bi*DCB + d];
                double diff = zev - zqv;
                ssum += diff*diff;
            }
            atomicAdd(&lossS[b], ssum);
        }
    }
}

// ---------------- kernel 6: out-projection + loss write ---------------------
__global__ __launch_bounds__(256) void k_out_proj(
    const float* __restrict__ cb, const float* __restrict__ ze,
    const int* __restrict__ idx_i, const float* __restrict__ w_out,
    const float* __restrict__ out_b, const double* __restrict__ lossS,
    float* __restrict__ zq_out, float* __restrict__ commit_out,
    float* __restrict__ cbloss_out)
{
    __shared__ float wl[128*DCB];
    __shared__ float bl[128];
    int tid = threadIdx.x;

    if (blockIdx.x == 0 && blockIdx.y == 0 && tid < BB) {
        double m = lossS[tid] / (double)(DCB*TT);
        commit_out[tid] = (float)(m * 0.005);
        cbloss_out[tid] = (float)m;
    }

    int oc = blockIdx.y;
    int obase = oc*128;
    for (int x = tid; x < 128*DCB; x += 256) wl[x] = w_out[obase*DCB + x];
    for (int x = tid; x < 128; x += 256) bl[x] = out_b[obase + x];
    __syncthreads();

    int pos = blockIdx.x*256 + tid;
    int b = pos >> 11, t = pos & (TT-1);
    int ki = idx_i[pos];
    float zq[DCB];
    #pragma unroll
    for (int d = 0; d < DCB; ++d) {
        float zev = ze[((size_t)b*DCB + d)*TT + t];
        float zqv = cb[ki*DCB + d];
        zq[d] = zev + (zqv - zev);
    }
    float* outp = zq_out + ((size_t)b*DIN + obase)*TT + t;
    for (int oo = 0; oo < 128; ++oo) {
        float acc = 0.f;
        #pragma unroll
        for (int d = 0; d < DCB; ++d) acc += wl[oo*DCB + d]*zq[d];
        acc += bl[oo];
        outp[(size_t)oo*TT] = acc;
    }
}

// ---------------- launch ----------------------------------------------------
extern "C" void kernel_launch(void* const* d_in, const int* in_sizes, int n_in,
                              void* d_out, int out_size, void* d_ws, size_t ws_size,
                              hipStream_t stream)
{
    const float* z        = (const float*)d_in[0];
    const float* in_v     = (const float*)d_in[1];
    const float* in_g     = (const float*)d_in[2];
    const float* in_b     = (const float*)d_in[3];
    const float* out_v    = (const float*)d_in[4];
    const float* out_g    = (const float*)d_in[5];
    const float* out_b    = (const float*)d_in[6];
    const float* codebook = (const float*)d_in[7];

    float* out = (float*)d_out;
    float* zq_out_p  = out + OFF_ZQOUT;
    float* commit_p  = out + OFF_COMMIT;
    float* cbloss_p  = out + OFF_CBLOSS;
    float* idx_p     = out + OFF_IDX;
    float* ze_p      = out + OFF_ZE;

    // workspace layout (doubles first)
    double* w_in_d = (double*)d_ws;                     // 8192
    double* cb_n   = w_in_d + DCB*DIN;                  // 65536
    double* s_k    = cb_n + (size_t)KK*DCB;             // 8192
    double* enc_n  = s_k + KK;                          // 131072
    double* q_s    = enc_n + (size_t)NPOS*DCB;          // 16384
    double* lossS  = q_s + NPOS;                        // 16
    float*  w_out  = (float*)(lossS + 16);              // 8192
    float*  cbn_f  = w_out + DCB*DIN;                   // 65536
    float*  skp_f  = cbn_f + (size_t)KK*DCB;            // 8192
    float*  enc2_f = skp_f + KK;                        // 131072
    int*    d1key  = (int*)(enc2_f + (size_t)NPOS*DCB); // 64*16384
    int*    d2key  = d1key + (size_t)KCHUNKS*NPOS;      // 64*16384
    int*    flaglist = d2key + (size_t)KCHUNKS*NPOS;    // 16384
    int*    counter  = flaglist + NPOS;                 // 1 (+pad)
    int*    idx_i    = counter + 16;                    // 16384

    k_prep<<<44, 256, 0, stream>>>(in_v, in_g, out_v, out_g, codebook,
                                   w_in_d, w_out, cb_n, s_k, cbn_f, skp_f,
                                   lossS, counter);
    k_inproj<<<NPOS/32, 256, 0, stream>>>(z, w_in_d, in_b, ze_p, enc_n, q_s, enc2_f);
    k_argmin32<<<dim3(16, KCHUNKS), 256, 0, stream>>>(enc2_f, cbn_f, skp_f, d1key, d2key);
    k_merge<<<NPOS/256, 256, 0, stream>>>(d1key, d2key, codebook, ze_p,
                                          idx_p, idx_i, flaglist, counter, lossS);
    k_refine<<<128, 256, 0, stream>>>(enc_n, q_s, cb_n, s_k, codebook, ze_p,
                                      flaglist, counter, idx_p, idx_i, lossS);
    k_out_proj<<<dim3(NPOS/256, DIN/128), 256, 0, stream>>>(
        codebook, ze_p, idx_i, w_out, out_b, lossS,
        zq_out_p, commit_p, cbloss_p);
}

// Round 3
// 241.662 us; speedup vs baseline: 1.1484x; 1.1484x over previous
//
#include <hip/hip_runtime.h>
#include <math.h>
#include <stdint.h>

// Problem constants
#define BB    8
#define DIN   1024
#define TT    2048
#define KK    8192
#define DCB   8
#define NPOS  (BB*TT)         // 16384
#define KCHUNKS 64
#define KCH     (KK/KCHUNKS)  // 128
#define MARGIN  3e-4f         // covers 2x (fp32 eval err ~1e-5 + 7-bit packing err ~1.2e-4)

// d_out layout (float32):
#define OFF_ZQOUT  0
#define OFF_COMMIT 16777216
#define OFF_CBLOSS 16777224
#define OFF_IDX    16777232
#define OFF_ZE     16793616

// ---------------- kernel 1: prep (44 blocks, parallel roles) ----------------
__global__ __launch_bounds__(256) void k_prep(
    const float* __restrict__ in_v, const float* __restrict__ in_g,
    const float* __restrict__ out_v, const float* __restrict__ out_g,
    const float* __restrict__ cb,
    double* __restrict__ w_in_d, float* __restrict__ w_out_f,
    double* __restrict__ cb_n, double* __restrict__ s_k,
    float* __restrict__ cbn_f, float* __restrict__ skp_f,
    double* __restrict__ lossS, int* __restrict__ counter)
{
    __shared__ double red[256];
    int tid = threadIdx.x;
    int blk = blockIdx.x;
    if (blk == 0) {
        if (tid < 16) lossS[tid] = 0.0;
        if (tid == 16) *counter = 0;
    }
    if (blk < 8) {
        int r = blk;
        double s = 0.0;
        for (int i = tid; i < DIN; i += 256) {
            double v = (double)in_v[r*DIN + i];
            s += v*v;
        }
        red[tid] = s; __syncthreads();
        for (int off = 128; off > 0; off >>= 1) {
            if (tid < off) red[tid] += red[tid+off];
            __syncthreads();
        }
        double scale = (double)in_g[r] / sqrt(red[0]);
        for (int i = tid; i < DIN; i += 256)
            w_in_d[r*DIN + i] = scale * (double)in_v[r*DIN + i];
    } else if (blk < 12) {
        int o = (blk-8)*256 + tid;
        float vv[DCB];
        double s = 0.0;
        #pragma unroll
        for (int d = 0; d < DCB; ++d) {
            vv[d] = out_v[o*DCB + d];
            s += (double)vv[d]*(double)vv[d];
        }
        double scale = (double)out_g[o] / sqrt(s);
        #pragma unroll
        for (int d = 0; d < DCB; ++d)
            w_out_f[o*DCB + d] = (float)(scale * (double)vv[d]);
    } else {
        int k = (blk-12)*256 + tid;
        double v[DCB]; double s = 0.0;
        #pragma unroll
        for (int d = 0; d < DCB; ++d) {
            v[d] = (double)cb[k*DCB + d];
            s += v[d]*v[d];
        }
        double nrm = sqrt(s);
        if (nrm < 1e-12) nrm = 1e-12;
        double s2 = 0.0;
        #pragma unroll
        for (int d = 0; d < DCB; ++d) {
            double t = v[d] / nrm;
            cb_n[(size_t)k*DCB + d] = t;
            cbn_f[(size_t)k*DCB + d] = (float)t;
            s2 += t*t;
        }
        s_k[k] = s2;
        skp_f[k] = (float)(s2 + 4.0);   // shift => dist' = skp - 2*dot > 0 always
    }
}

// ---------------- kernel 2: fused in-projection + reduce (fp64) -------------
// Summation order identical to R1/R2 (passed) => bit-identical z_e/enc_n/q_s.
__global__ __launch_bounds__(256) void k_inproj(
    const float* __restrict__ z, const double* __restrict__ w_in_d,
    const float* __restrict__ in_b,
    float* __restrict__ ze_out, double* __restrict__ enc_n,
    double* __restrict__ q_s, float* __restrict__ enc2_f)
{
    __shared__ double wl[DIN*DCB];   // 64 KB
    __shared__ double red[2048];     // 16 KB

    int tid = threadIdx.x;
    for (int x = tid; x < DIN*DCB; x += 256) wl[x] = w_in_d[x];
    __syncthreads();

    int p = tid & 31;
    int q = tid >> 5;
    int pos = blockIdx.x*32 + p;
    int b = pos >> 11, t = pos & (TT-1);

    const float* zp = z + ((size_t)b*DIN + (size_t)q*128)*TT + t;
    double acc[DCB] = {0,0,0,0,0,0,0,0};
    for (int ii = 0; ii < 128; ++ii) {
        double zv = (double)zp[(size_t)ii*TT];
        int wbase = q*128 + ii;
        #pragma unroll
        for (int o = 0; o < DCB; ++o) acc[o] += wl[o*DIN + wbase] * zv;
    }
    #pragma unroll
    for (int o = 0; o < DCB; ++o) red[(q*32 + p)*DCB + o] = acc[o];
    __syncthreads();

    int p2 = tid >> 3, o2 = tid & 7;
    double s = 0.0;
    for (int q2 = 0; q2 < 8; ++q2) s += red[(q2*32 + p2)*DCB + o2];
    s += (double)in_b[o2];
    __syncthreads();
    red[p2*DCB + o2] = s;
    __syncthreads();

    if (tid < 32) {
        int pos3 = blockIdx.x*32 + tid;
        int b3 = pos3 >> 11, t3 = pos3 & (TT-1);
        double v[DCB]; double n2 = 0.0;
        #pragma unroll
        for (int o = 0; o < DCB; ++o) {
            v[o] = red[tid*DCB + o];
            n2 += v[o]*v[o];
            ze_out[((size_t)b3*DCB + o)*TT + t3] = (float)v[o];
        }
        double nrm = sqrt(n2);
        if (nrm < 1e-12) nrm = 1e-12;
        double s2 = 0.0;
        #pragma unroll
        for (int o = 0; o < DCB; ++o) {
            double e = v[o] / nrm;
            enc_n[(size_t)pos3*DCB + o] = e;
            enc2_f[(size_t)pos3*DCB + o] = (float)(-2.0 * e);
            s2 += e*e;
        }
        q_s[pos3] = s2;
    }
}

// ---------------- kernel 3: fp32 packed-key argmin screen --------------------
// grid (32 qtiles, 64 kchunks) = 2048 blocks (8/CU), 2 queries/thread.
__global__ __launch_bounds__(256, 8) void k_argmin32(
    const float* __restrict__ enc2_f, const float* __restrict__ cbn_f,
    const float* __restrict__ skp_f,
    int* __restrict__ d1key, int* __restrict__ d2key)
{
    __shared__ float cbl[KCH*DCB];   // 4 KB
    __shared__ float skl[KCH];       // 512 B
    int tid = threadIdx.x;
    int qt = blockIdx.x, kc = blockIdx.y, kbase = kc*KCH;

    for (int x = tid; x < KCH*DCB; x += 256) cbl[x] = cbn_f[(size_t)kbase*DCB + x];
    for (int x = tid; x < KCH; x += 256) skl[x] = skp_f[kbase + x];
    __syncthreads();

    float e[2][DCB]; int d1[2], d2[2];
    #pragma unroll
    for (int j = 0; j < 2; ++j) {
        int qq = qt*512 + j*256 + tid;
        #pragma unroll
        for (int d = 0; d < DCB; ++d) e[j][d] = enc2_f[(size_t)qq*DCB + d];
        d1[j] = 0x7F800000; d2[j] = 0x7F800000;
    }

    const float4* cb4 = (const float4*)cbl;
    for (int kk = 0; kk < KCH; ++kk) {
        float4 ca = cb4[kk*2], cbv = cb4[kk*2+1];
        float sk = skl[kk];
        #pragma unroll
        for (int j = 0; j < 2; ++j) {
            float acc = sk;
            acc = fmaf(ca.x,  e[j][0], acc);
            acc = fmaf(ca.y,  e[j][1], acc);
            acc = fmaf(ca.z,  e[j][2], acc);
            acc = fmaf(ca.w,  e[j][3], acc);
            acc = fmaf(cbv.x, e[j][4], acc);
            acc = fmaf(cbv.y, e[j][5], acc);
            acc = fmaf(cbv.z, e[j][6], acc);
            acc = fmaf(cbv.w, e[j][7], acc);
            int key = (int)((__float_as_uint(acc) & 0xFFFFFF80u) | (unsigned)kk);
            int m = max(key, d1[j]);
            d2[j] = min(d2[j], m);
            d1[j] = min(d1[j], key);
        }
    }
    #pragma unroll
    for (int j = 0; j < 2; ++j) {
        int qq = qt*512 + j*256 + tid;
        d1key[(size_t)kc*NPOS + qq] = d1[j];
        d2key[(size_t)kc*NPOS + qq] = d2[j];
    }
}

// ---------------- kernel 4: merge chunks, flag near-ties, loss (unflagged) --
// grid 128 blocks x 128 threads.
__global__ __launch_bounds__(128) void k_merge(
    const int* __restrict__ d1key, const int* __restrict__ d2key,
    const float* __restrict__ cb, const float* __restrict__ ze,
    float* __restrict__ idx_f, int* __restrict__ idx_i,
    int* __restrict__ flaglist, int* __restrict__ counter,
    double* __restrict__ lossS)
{
    __shared__ double red[128];
    int tid = threadIdx.x;
    int pos = blockIdx.x*128 + tid;
    int b = pos >> 11, t = pos & (TT-1);

    int bits1 = 0x7F800000, bits2 = 0x7F800000, gi = 0;
    for (int c = 0; c < KCHUNKS; ++c) {    // ascending => first-min on ties
        int k1 = d1key[(size_t)c*NPOS + pos];
        int k2 = d2key[(size_t)c*NPOS + pos];
        int db = k1 & 0xFFFFFF80;
        int b2 = k2 & 0xFFFFFF80;
        if (db < bits1) {
            bits2 = min(bits2, min(bits1, b2));
            bits1 = db;
            gi = c*KCH + (k1 & 0x7F);
        } else {
            bits2 = min(bits2, db);
        }
    }
    float d1f = __int_as_float(bits1);
    float d2f = __int_as_float(bits2);
    bool flag = (d2f - d1f) < MARGIN;

    idx_f[pos] = (float)gi;     // provisional; refine overwrites flagged
    idx_i[pos] = gi;
    if (flag) {
        int s = atomicAdd(counter, 1);
        flaglist[s] = pos;
    }

    double ssum = 0.0;
    if (!flag) {
        #pragma unroll
        for (int d = 0; d < DCB; ++d) {
            double zev = (double)ze[((size_t)b*DCB + d)*TT + t];
            double zqv = (double)cb[gi*DCB + d];
            double diff = zev - zqv;
            ssum += diff*diff;
        }
    }
    red[tid] = ssum; __syncthreads();
    for (int off = 64; off > 0; off >>= 1) {
        if (tid < off) red[tid] += red[tid+off];
        __syncthreads();
    }
    if (tid == 0) atomicAdd(&lossS[b], red[0]);
}

// ---------------- kernel 5: fp64 refine via chunk-key shortlist --------------
// One wave per flagged query. Lane c holds chunk c's stored top-2 keys:
//  - chunk d1 within thr  -> evaluate that single code in fp64
//  - chunk d2 within thr  -> full 128-code fp64 rescan of that chunk
//    (covers any 3rd-in-chunk candidate hidden behind the stored top-2)
__device__ __forceinline__ double eval_dist64(
    const double* __restrict__ e, double qs,
    const double* __restrict__ cb_n, const double* __restrict__ s_k, int k)
{
    const double* c = cb_n + (size_t)k*DCB;
    double dot = e[0]*c[0] + e[1]*c[1] + e[2]*c[2] + e[3]*c[3]
               + e[4]*c[4] + e[5]*c[5] + e[6]*c[6] + e[7]*c[7];
    return qs - 2.0*dot + s_k[k];
}

__global__ __launch_bounds__(256) void k_refine(
    const double* __restrict__ enc_n, const double* __restrict__ q_s,
    const double* __restrict__ cb_n, const double* __restrict__ s_k,
    const float* __restrict__ cb, const float* __restrict__ ze,
    const int* __restrict__ d1key, const int* __restrict__ d2key,
    const int* __restrict__ flaglist, const int* __restrict__ counter,
    float* __restrict__ idx_f, int* __restrict__ idx_i,
    double* __restrict__ lossS)
{
    int tid = threadIdx.x;
    int lane = tid & 63;
    int wave = blockIdx.x*4 + (tid >> 6);
    int nwaves = gridDim.x*4;
    int n = *counter;

    for (int f = wave; f < n; f += nwaves) {
        int pos = flaglist[f];
        double e[DCB];
        #pragma unroll
        for (int d = 0; d < DCB; ++d) e[d] = enc_n[(size_t)pos*DCB + d];
        double qs = q_s[pos];

        // lane `lane` owns chunk `lane` (KCHUNKS == 64)
        int k1 = d1key[(size_t)lane*NPOS + pos];
        int k2 = d2key[(size_t)lane*NPOS + pos];
        int hb1 = k1 & 0xFFFFFF80;

        // global best packed distance across chunks
        int m1 = hb1;
        #pragma unroll
        for (int off = 32; off > 0; off >>= 1)
            m1 = min(m1, __shfl_xor(m1, off, 64));
        float thr = __int_as_float(m1) + MARGIN;

        bool cand   = __int_as_float(hb1) <= thr;
        bool rescan = __int_as_float(k2 & 0xFFFFFF80) <= thr;

        double bd = 1e300; int bi = 0x7FFFFFFF;
        if (cand) {
            int k = lane*KCH + (k1 & 0x7F);
            double d = eval_dist64(e, qs, cb_n, s_k, k);
            bd = d; bi = k;
        }
        unsigned long long rmask = __ballot(rescan);
        while (rmask) {
            int c = __ffsll((long long)rmask) - 1;
            rmask &= rmask - 1;
            #pragma unroll
            for (int r = 0; r < KCH/64; ++r) {
                int k = c*KCH + r*64 + lane;
                double d = eval_dist64(e, qs, cb_n, s_k, k);
                if (d < bd || (d == bd && k < bi)) { bd = d; bi = k; }
            }
        }
        // wave-wide lexicographic min (dist, k) == sequential first-min
        #pragma unroll
        for (int off = 32; off > 0; off >>= 1) {
            double od = __shfl_xor(bd, off, 64);
            int    oi = __shfl_xor(bi, off, 64);
            if (od < bd || (od == bd && oi < bi)) { bd = od; bi = oi; }
        }
        if (lane == 0) {
            int b = pos >> 11, t = pos & (TT-1);
            idx_f[pos] = (float)bi;
            idx_i[pos] = bi;
            double ssum = 0.0;
            #pragma unroll
            for (int d = 0; d < DCB; ++d) {
                double zev = (double)ze[((size_t)b*DCB + d)*TT + t];
                double zqv = (double)cb[bi*DCB + d];
                double diff = zev - zqv;
                ssum += diff*diff;
            }
            atomicAdd(&lossS[b], ssum);
        }
    }
}

// ---------------- kernel 6: out-projection + loss write ---------------------
__global__ __launch_bounds__(256) void k_out_proj(
    const float* __restrict__ cb, const float* __restrict__ ze,
    const int* __restrict__ idx_i, const float* __restrict__ w_out,
    const float* __restrict__ out_b, const double* __restrict__ lossS,
    float* __restrict__ zq_out, float* __restrict__ commit_out,
    float* __restrict__ cbloss_out)
{
    __shared__ float wl[128*DCB];
    __shared__ float bl[128];
    int tid = threadIdx.x;

    if (blockIdx.x == 0 && blockIdx.y == 0 && tid < BB) {
        double m = lossS[tid] / (double)(DCB*TT);
        commit_out[tid] = (float)(m * 0.005);
        cbloss_out[tid] = (float)m;
    }

    int oc = blockIdx.y;
    int obase = oc*128;
    for (int x = tid; x < 128*DCB; x += 256) wl[x] = w_out[obase*DCB + x];
    for (int x = tid; x < 128; x += 256) bl[x] = out_b[obase + x];
    __syncthreads();

    int pos = blockIdx.x*256 + tid;
    int b = pos >> 11, t = pos & (TT-1);
    int ki = idx_i[pos];
    float zq[DCB];
    #pragma unroll
    for (int d = 0; d < DCB; ++d) {
        float zev = ze[((size_t)b*DCB + d)*TT + t];
        float zqv = cb[ki*DCB + d];
        zq[d] = zev + (zqv - zev);
    }
    float* outp = zq_out + ((size_t)b*DIN + obase)*TT + t;
    for (int oo = 0; oo < 128; ++oo) {
        float acc = 0.f;
        #pragma unroll
        for (int d = 0; d < DCB; ++d) acc += wl[oo*DCB + d]*zq[d];
        acc += bl[oo];
        outp[(size_t)oo*TT] = acc;
    }
}

// ---------------- launch ----------------------------------------------------
extern "C" void kernel_launch(void* const* d_in, const int* in_sizes, int n_in,
                              void* d_out, int out_size, void* d_ws, size_t ws_size,
                              hipStream_t stream)
{
    const float* z        = (const float*)d_in[0];
    const float* in_v     = (const float*)d_in[1];
    const float* in_g     = (const float*)d_in[2];
    const float* in_b     = (const float*)d_in[3];
    const float* out_v    = (const float*)d_in[4];
    const float* out_g    = (const float*)d_in[5];
    const float* out_b    = (const float*)d_in[6];
    const float* codebook = (const float*)d_in[7];

    float* out = (float*)d_out;
    float* zq_out_p  = out + OFF_ZQOUT;
    float* commit_p  = out + OFF_COMMIT;
    float* cbloss_p  = out + OFF_CBLOSS;
    float* idx_p     = out + OFF_IDX;
    float* ze_p      = out + OFF_ZE;

    // workspace layout (doubles first)
    double* w_in_d = (double*)d_ws;                     // 8192
    double* cb_n   = w_in_d + DCB*DIN;                  // 65536
    double* s_k    = cb_n + (size_t)KK*DCB;             // 8192
    double* enc_n  = s_k + KK;                          // 131072
    double* q_s    = enc_n + (size_t)NPOS*DCB;          // 16384
    double* lossS  = q_s + NPOS;                        // 16
    float*  w_out  = (float*)(lossS + 16);              // 8192
    float*  cbn_f  = w_out + DCB*DIN;                   // 65536
    float*  skp_f  = cbn_f + (size_t)KK*DCB;            // 8192
    float*  enc2_f = skp_f + KK;                        // 131072
    int*    d1key  = (int*)(enc2_f + (size_t)NPOS*DCB); // 64*16384
    int*    d2key  = d1key + (size_t)KCHUNKS*NPOS;      // 64*16384
    int*    flaglist = d2key + (size_t)KCHUNKS*NPOS;    // 16384
    int*    counter  = flaglist + NPOS;                 // 1 (+pad)
    int*    idx_i    = counter + 16;                    // 16384

    k_prep<<<44, 256, 0, stream>>>(in_v, in_g, out_v, out_g, codebook,
                                   w_in_d, w_out, cb_n, s_k, cbn_f, skp_f,
                                   lossS, counter);
    k_inproj<<<NPOS/32, 256, 0, stream>>>(z, w_in_d, in_b, ze_p, enc_n, q_s, enc2_f);
    k_argmin32<<<dim3(32, KCHUNKS), 256, 0, stream>>>(enc2_f, cbn_f, skp_f, d1key, d2key);
    k_merge<<<NPOS/128, 128, 0, stream>>>(d1key, d2key, codebook, ze_p,
                                          idx_p, idx_i, flaglist, counter, lossS);
    k_refine<<<256, 256, 0, stream>>>(enc_n, q_s, cb_n, s_k, codebook, ze_p,
                                      d1key, d2key, flaglist, counter,
                                      idx_p, idx_i, lossS);
    k_out_proj<<<dim3(NPOS/256, DIN/128), 256, 0, stream>>>(
        codebook, ze_p, idx_i, w_out, out_b, lossS,
        zq_out_p, commit_p, cbloss_p);
}